// Round 1
// baseline (518.218 us; speedup 1.0000x reference)
//
#include <hip/hip_runtime.h>
#include <cstdint>
#include <cstddef>

typedef __bf16 bf16;
typedef __bf16 bf16x4 __attribute__((ext_vector_type(4)));
typedef __bf16 bf16x8 __attribute__((ext_vector_type(8)));
typedef float  f32x4  __attribute__((ext_vector_type(4)));
typedef unsigned int uint;

#define EPS 1e-5f

// ---------------------------------------------------------------------------
// async global->LDS, 16B per lane. LDS dest is wave-uniform base + lane*16.
// ---------------------------------------------------------------------------
__device__ __forceinline__ void load_lds16(const void* g, void* l) {
    typedef __attribute__((address_space(1))) void gvoid;
    typedef __attribute__((address_space(3))) void lvoid;
    gvoid* gp = (gvoid*)(unsigned long long)(uintptr_t)g;
    lvoid* lp = (lvoid*)(unsigned int)(uintptr_t)l;
    __builtin_amdgcn_global_load_lds(gp, lp, 16, 0, 0);
}

// ---------------------------------------------------------------------------
// fused: x -> bf16 copy + per-(b,d) partial sums for mean/std. grid (64,16)
// ---------------------------------------------------------------------------
__global__ __launch_bounds__(256)
void convert_stats(const float* __restrict__ x, bf16* __restrict__ xb,
                   float* __restrict__ p1, float* __restrict__ p2)
{
    const int b = blockIdx.x, lc = blockIdx.y, d = threadIdx.x;
    const size_t base = ((size_t)b * 1024 + lc * 64) * 256;
    float s = 0.f, s2 = 0.f;
    #pragma unroll 4
    for (int l = 0; l < 64; l++) {
        float v = x[base + (size_t)l * 256 + d];
        xb[base + (size_t)l * 256 + d] = (bf16)v;
        s += v; s2 += v * v;
    }
    p1[((size_t)lc * 64 + b) * 256 + d] = s;
    p2[((size_t)lc * 64 + b) * 256 + d] = s2;
}

// ---------------------------------------------------------------------------
// all weight prep in ONE dispatch: 4 transposes + 4 scale/bias. 3592 blocks.
// ---------------------------------------------------------------------------
__global__ void prep_all(
    const float* __restrict__ W1, const float* __restrict__ W2,
    const float* __restrict__ W3, const float* __restrict__ W4,
    bf16* __restrict__ t1, bf16* __restrict__ t2,
    bf16* __restrict__ t3, bf16* __restrict__ t4,
    const float* b1, const float* g1, const float* be1, const float* m1, const float* v1,
    const float* b2, const float* g2, const float* be2, const float* m2, const float* v2,
    const float* b3, const float* g3, const float* be3, const float* m3, const float* v3,
    const float* b4, const float* g4, const float* be4, const float* m4, const float* v4,
    float* __restrict__ sb)
{
    const int bid = blockIdx.x, tid = threadIdx.x;
    if (bid < 512) {                       // W1: 512x256 (Wt[n][k])
        int idx = bid * 256 + tid;
        int n = idx >> 8, k = idx & 255;
        t1[idx] = (bf16)W1[k * 512 + n];
    } else if (bid < 3584) {               // W2/W3/W4: 512x512 each
        int r = bid - 512;
        int which = r >> 10;               // 1024 blocks each
        int idx = (r & 1023) * 256 + tid;
        int n = idx >> 9, k = idx & 511;
        const float* W = which == 0 ? W2 : (which == 1 ? W3 : W4);
        bf16* Wt       = which == 0 ? t2 : (which == 1 ? t3 : t4);
        Wt[idx] = (bf16)W[k * 512 + n];
    } else {                               // scale/bias: 8 blocks
        int r = bid - 3584;
        int lay = r >> 1;
        int j = (r & 1) * 256 + tid;
        const float *b, *g, *be, *m, *v;
        switch (lay) {
            case 0: b=b1; g=g1; be=be1; m=m1; v=v1; break;
            case 1: b=b2; g=g2; be=be2; m=m2; v=v2; break;
            case 2: b=b3; g=g3; be=be3; m=m3; v=v3; break;
            default:b=b4; g=g4; be=be4; m=m4; v=v4; break;
        }
        float sj = g[j] * rsqrtf(v[j] + EPS);
        sb[lay * 1024 + j]       = sj;
        sb[lay * 1024 + 512 + j] = (b[j] - m[j]) * sj + be[j];
    }
}

// ---------------------------------------------------------------------------
// GEMM: C[M,512] = relu( (A[M,K] @ Wt[512,K]^T) * s + t ), bf16 out
// 128x256 tile, BK=32. 512 threads = 8 waves as 2m x 4n; wave tile 64x64;
// acc 4x4 f32x4 (64 regs) -> __launch_bounds__(512,4) = 2 blocks/CU = 50% occ.
//
// LDS is SUBTILED per 16-row block: [blk][quad][l16][8 bf16] so every
// ds_read_b128 has the 64 lanes reading consecutive 16B (2 lanes/bank = free,
// m136) instead of the 8-way conflict of the row-major [row][32] layout.
// global_load_lds writes linearly (lane*16), so the subtiling is applied by
// permuting the per-lane GLOBAL source address (rule 21: both-sides-or-
// neither); the wave still touches the same 16 rows x 64B -> coalescing
// unchanged.
//   LDS byte tid*16  <->  A[row = (tid>>6)*16 + (tid&15)][k0 + ((tid>>4)&3)*8]
// ---------------------------------------------------------------------------
template<int K>
__global__ __launch_bounds__(512, 4)
void gemm_bt(const bf16* __restrict__ A, const bf16* __restrict__ Bt,
             const float* __restrict__ sc, const float* __restrict__ bi,
             bf16* __restrict__ C)
{
    __shared__ __align__(16) bf16 As[128 * 32];   // 8 KB : 8 subtile blocks
    __shared__ __align__(16) bf16 Bs[256 * 32];   // 16 KB: 16 subtile blocks

    const int tid  = threadIdx.x;
    const int lane = tid & 63;
    const int wid  = tid >> 6;            // 0..7
    const int wm   = wid >> 2;            // 0..1 (m half)
    const int wn   = wid & 3;             // 0..3 (n quarter)
    const size_t m0 = (size_t)blockIdx.x * 128;
    const int    n0 = blockIdx.y * 256;

    const int quad = lane >> 4;
    const int l16  = lane & 15;

    // staging: source row/col for this lane's 16B (subtiled permutation)
    const int srow = wid * 16 + l16;      // 0..127
    const int scol = quad * 8;            // 0,8,16,24

    bf16* AsW = &As[(tid & 448) * 8];     // wave-uniform: wid*1024 bytes
    bf16* BsW = &Bs[(tid & 448) * 8];

    f32x4 acc[4][4] = {};

    for (int k0 = 0; k0 < K; k0 += 32) {
        load_lds16(&A [(m0 + srow) * K + k0 + scol], AsW);
        load_lds16(&Bt[(size_t)(n0 +       srow) * K + k0 + scol], BsW);
        load_lds16(&Bt[(size_t)(n0 + 128 + srow) * K + k0 + scol], BsW + 4096);
        __syncthreads();   // drains vmcnt -> LDS visible

        // conflict-free fragment reads: 64 lanes -> consecutive 16B
        bf16x8 af[4], bfr[4];
        #pragma unroll
        for (int i = 0; i < 4; i++)
            af[i] = *(const bf16x8*)&As[((wm * 4 + i) * 64 + lane) * 8];
        #pragma unroll
        for (int j = 0; j < 4; j++)
            bfr[j] = *(const bf16x8*)&Bs[((wn * 4 + j) * 64 + lane) * 8];
        #pragma unroll
        for (int i = 0; i < 4; i++)
            #pragma unroll
            for (int j = 0; j < 4; j++)
                acc[i][j] = __builtin_amdgcn_mfma_f32_16x16x32_bf16(af[i], bfr[j], acc[i][j], 0, 0, 0);
        __syncthreads();   // before next staging overwrites LDS
    }

    // epilogue: C/D layout col = lane&15, row = quad*4 + r  [m89/m91 verified]
    #pragma unroll
    for (int j = 0; j < 4; j++) {
        const int col = n0 + wn * 64 + j * 16 + l16;
        const float s = sc[col], t = bi[col];
        #pragma unroll
        for (int i = 0; i < 4; i++) {
            const size_t rowb = m0 + wm * 64 + i * 16 + quad * 4;
            #pragma unroll
            for (int r = 0; r < 4; r++) {
                float v = acc[i][j][r] * s + t;
                v = v > 0.f ? v : 0.f;
                C[(rowb + r) * 512 + col] = (bf16)v;
            }
        }
    }
}

// ---------------------------------------------------------------------------
// A[N,8] = h4[N,512](bf16) @ Wa[512,8](f32)
// ---------------------------------------------------------------------------
__global__ __launch_bounds__(256)
void compute_A(const bf16* __restrict__ h, const float* __restrict__ Wa,
               float* __restrict__ A)
{
    __shared__ float WaL[512 * 8];
    const int tid = threadIdx.x;
    for (int i = tid; i < 4096; i += 256) WaL[i] = Wa[i];
    __syncthreads();
    const size_t row = (size_t)blockIdx.x * 32 + (tid >> 3);
    const int r = tid & 7;
    const bf16* hp = h + row * 512;
    float acc0 = 0.f, acc1 = 0.f;
    #pragma unroll 4
    for (int k8 = 0; k8 < 64; k8 += 2) {
        bf16x8 h0 = *(const bf16x8*)&hp[k8 * 8];
        bf16x8 h1 = *(const bf16x8*)&hp[k8 * 8 + 8];
        #pragma unroll
        for (int j = 0; j < 8; j++) {
            acc0 += (float)h0[j] * WaL[(k8 * 8 + j) * 8 + r];
            acc1 += (float)h1[j] * WaL[(k8 * 8 + 8 + j) * 8 + r];
        }
    }
    A[row * 8 + r] = acc0 + acc1;
}

// ---------------------------------------------------------------------------
// per-segment softmax over L (8 cols) + penalty. 1024 threads.
// ---------------------------------------------------------------------------
__global__ __launch_bounds__(1024)
void seg_softmax(const float* __restrict__ A, float* __restrict__ Asg,
                 float* __restrict__ pen)
{
    __shared__ float AsL[8192];
    __shared__ float red[1024];
    __shared__ float amax[8], asum[8];
    const int b = blockIdx.x, tid = threadIdx.x;
    const float* Ab = A + (size_t)b * 8192;
    for (int i = tid * 4; i < 8192; i += 4096)
        *(float4*)&AsL[i] = *(const float4*)&Ab[i];
    __syncthreads();
    const int r = tid & 7, chunk = tid >> 3;      // 128 chunks x 8 rows
    float pm = -1e30f;
    for (int l = chunk * 8; l < chunk * 8 + 8; l++) pm = fmaxf(pm, AsL[l * 8 + r]);
    red[tid] = pm;
    __syncthreads();
    if (tid < 512) red[tid] = fmaxf(red[tid], red[tid + 512]); __syncthreads();
    if (tid < 256) red[tid] = fmaxf(red[tid], red[tid + 256]); __syncthreads();
    if (tid < 128) red[tid] = fmaxf(red[tid], red[tid + 128]); __syncthreads();
    if (tid <  64) red[tid] = fmaxf(red[tid], red[tid +  64]); __syncthreads();
    if (tid <  32) red[tid] = fmaxf(red[tid], red[tid +  32]); __syncthreads();
    if (tid <  16) red[tid] = fmaxf(red[tid], red[tid +  16]); __syncthreads();
    if (tid <   8) amax[tid] = fmaxf(red[tid], red[tid + 8]);  __syncthreads();
    const float mr = amax[r];
    float ps = 0.f;
    for (int l = chunk * 8; l < chunk * 8 + 8; l++) {
        float e = expf(AsL[l * 8 + r] - mr);
        AsL[l * 8 + r] = e;
        ps += e;
    }
    red[tid] = ps;
    __syncthreads();
    if (tid < 512) red[tid] += red[tid + 512]; __syncthreads();
    if (tid < 256) red[tid] += red[tid + 256]; __syncthreads();
    if (tid < 128) red[tid] += red[tid + 128]; __syncthreads();
    if (tid <  64) red[tid] += red[tid +  64]; __syncthreads();
    if (tid <  32) red[tid] += red[tid +  32]; __syncthreads();
    if (tid <  16) red[tid] += red[tid +  16]; __syncthreads();
    if (tid <   8) asum[tid] = red[tid] + red[tid + 8];        __syncthreads();
    const float inv = 1.f / asum[r];
    for (int l = chunk * 8; l < chunk * 8 + 8; l++) AsL[l * 8 + r] *= inv;
    __syncthreads();
    for (int i = tid * 4; i < 8192; i += 4096)
        *(float4*)&Asg[(size_t)b * 8192 + i] = *(const float4*)&AsL[i];
    __syncthreads();
    // penalty: 64 (rr,ss) pairs x 16 l-chunks of 64
    {
        const int p = tid & 63, ch = tid >> 6;
        const int rr = p >> 3, ss = p & 7;
        float dot = 0.f;
        for (int l = ch * 64; l < ch * 64 + 64; l++)
            dot += AsL[l * 8 + rr] * AsL[l * 8 + ss];
        red[tid] = dot;
    }
    __syncthreads();
    if (tid < 512) red[tid] += red[tid + 512]; __syncthreads();
    if (tid < 256) red[tid] += red[tid + 256]; __syncthreads();
    if (tid < 128) red[tid] += red[tid + 128]; __syncthreads();
    if (tid < 64) {
        float d = red[tid] + red[tid + 64] - 1.f;
        red[tid] = d * d;
    }
    __syncthreads();
    if (tid == 0) {
        float s = 0.f;
        for (int i = 0; i < 64; i++) s += red[i];
        atomicAdd(pen, s);
    }
}

// ---------------------------------------------------------------------------
// pooled partials: grid (64, 4 col-chunks, 8 l-chunks of 128)
// ---------------------------------------------------------------------------
__global__ __launch_bounds__(256)
void pooled_k(const float* __restrict__ Asg, const bf16* __restrict__ h,
              float* __restrict__ pp)
{
    const int b = blockIdx.x;
    const int cc0 = blockIdx.y * 128;
    const int lc = blockIdx.z;
    const int tid = threadIdx.x;
    const int c = tid & 127, rg = tid >> 7;
    float a0 = 0, a1 = 0, a2 = 0, a3 = 0;
    const float* Asb = Asg + (size_t)b * 8192 + (size_t)lc * 128 * 8 + rg * 4;
    const bf16* hb = h + ((size_t)b * 1024 + lc * 128) * 512 + cc0 + c;
    #pragma unroll 4
    for (int l = 0; l < 128; l++) {
        float4 a = *(const float4*)&Asb[(size_t)l * 8];
        float hv = (float)hb[(size_t)l * 512];
        a0 += a.x * hv; a1 += a.y * hv; a2 += a.z * hv; a3 += a.w * hv;
    }
    float* pb = pp + ((size_t)lc * 64 + b) * 4096 + (rg * 4) * 512 + cc0 + c;
    pb[0] = a0; pb[512] = a1; pb[1024] = a2; pb[1536] = a3;
}

// ---------------------------------------------------------------------------
// head pass 1: z[b][c] += feat-chunk @ Wo1-slice. grid (64, 9)
// kc==8 computes mean/std inline from the convert_stats partials.
// ---------------------------------------------------------------------------
__global__ __launch_bounds__(128)
void head1(const float* __restrict__ pp, const float* __restrict__ p1,
           const float* __restrict__ p2, const float* __restrict__ Wo1,
           float* __restrict__ zbuf)
{
    __shared__ float f[512];
    const int b = blockIdx.x, kc = blockIdx.y, tid = threadIdx.x;
    if (kc < 8) {
        for (int j = tid; j < 512; j += 128) {
            const size_t i = (size_t)kc * 512 + j;
            float s = 0.f;
            #pragma unroll
            for (int lc = 0; lc < 8; lc++)
                s += pp[((size_t)lc * 64 + b) * 4096 + i];
            f[j] = s;
        }
    } else {
        for (int j = tid; j < 256; j += 128) {
            float s = 0.f, s2 = 0.f;
            #pragma unroll
            for (int lc = 0; lc < 16; lc++) {
                s  += p1[((size_t)lc * 64 + b) * 256 + j];
                s2 += p2[((size_t)lc * 64 + b) * 256 + j];
            }
            float m = s * (1.f / 1024.f);
            float var = (s2 - s * m) * (1.f / 1023.f);
            f[j]       = m;
            f[256 + j] = sqrtf(fmaxf(var, 0.f));
        }
    }
    __syncthreads();
    const float* Wp = Wo1 + (size_t)kc * 512 * 128 + tid;
    float z = 0.f;
    #pragma unroll 8
    for (int j = 0; j < 512; j++) z += f[j] * Wp[(size_t)j * 128];
    atomicAdd(&zbuf[b * 128 + tid], z);
}

// ---------------------------------------------------------------------------
// head pass 2: BN+relu -> @ Wo2 -> log_softmax; b==0 writes penalty
// ---------------------------------------------------------------------------
__global__ __launch_bounds__(128)
void head2(const float* __restrict__ zbuf, const float* __restrict__ bo1,
           const float* __restrict__ go, const float* __restrict__ beo,
           const float* __restrict__ mo, const float* __restrict__ vo,
           const float* __restrict__ Wo2, const float* __restrict__ bo2,
           const float* __restrict__ pen, float* __restrict__ out)
{
    __shared__ float o[128];
    __shared__ float lg[4];
    const int b = blockIdx.x, tid = threadIdx.x;
    float z = zbuf[b * 128 + tid];
    float s = go[tid] * rsqrtf(vo[tid] + EPS);
    float t = (bo1[tid] - mo[tid]) * s + beo[tid];
    float ov = z * s + t;
    o[tid] = ov > 0.f ? ov : 0.f;
    __syncthreads();
    if (tid < 4) {
        float acc = bo2[tid];
        for (int j = 0; j < 128; j++) acc += o[j] * Wo2[j * 4 + tid];
        lg[tid] = acc;
    }
    __syncthreads();
    if (tid == 0) {
        float m = fmaxf(fmaxf(lg[0], lg[1]), fmaxf(lg[2], lg[3]));
        float sum = 0.f;
        for (int k = 0; k < 4; k++) sum += expf(lg[k] - m);
        float lse = m + logf(sum);
        for (int k = 0; k < 4; k++) out[b * 4 + k] = lg[k] - lse;
        if (b == 0) out[256] = pen[0];
    }
}

// ---------------------------------------------------------------------------
extern "C" void kernel_launch(void* const* d_in, const int* in_sizes, int n_in,
                              void* d_out, int out_size, void* d_ws, size_t ws_size,
                              hipStream_t stream)
{
    const float* x   = (const float*)d_in[0];
    const float* Wa  = (const float*)d_in[2];
    const float* Wo1 = (const float*)d_in[3];
    const float* bo1 = (const float*)d_in[4];
    const float* go  = (const float*)d_in[5];
    const float* beo = (const float*)d_in[6];
    const float* mo  = (const float*)d_in[7];
    const float* vo  = (const float*)d_in[8];
    const float* Wo2 = (const float*)d_in[9];
    const float* bo2 = (const float*)d_in[10];
    const float *W[4], *bb[4], *gg[4], *be[4], *mm[4], *vv[4];
    for (int l = 0; l < 4; l++) {
        W[l]  = (const float*)d_in[11 + 6 * l + 0];
        bb[l] = (const float*)d_in[11 + 6 * l + 1];
        gg[l] = (const float*)d_in[11 + 6 * l + 2];
        be[l] = (const float*)d_in[11 + 6 * l + 3];
        mm[l] = (const float*)d_in[11 + 6 * l + 4];
        vv[l] = (const float*)d_in[11 + 6 * l + 5];
    }

    char* w = (char*)d_ws;
    bf16* xb  = (bf16*)w;  w += (size_t)65536 * 256 * 2;   // 32 MB
    bf16* hA  = (bf16*)w;  w += (size_t)65536 * 512 * 2;   // 64 MB
    bf16* hB  = (bf16*)w;  w += (size_t)65536 * 512 * 2;   // 64 MB
    bf16* w1t = (bf16*)w;  w += (size_t)512 * 256 * 2;
    bf16* w2t = (bf16*)w;  w += (size_t)512 * 512 * 2;
    bf16* w3t = (bf16*)w;  w += (size_t)512 * 512 * 2;
    bf16* w4t = (bf16*)w;  w += (size_t)512 * 512 * 2;
    float* sb = (float*)w; w += (size_t)4 * 1024 * 4;      // [layer][s|t][512]
    float* Ab = (float*)w; w += (size_t)65536 * 8 * 4;
    float* As = (float*)w; w += (size_t)65536 * 8 * 4;
    float* pp = (float*)w; w += (size_t)8 * 64 * 4096 * 4; // pooled partials
    float* p1 = (float*)w; w += (size_t)16 * 64 * 256 * 4;
    float* p2 = (float*)w; w += (size_t)16 * 64 * 256 * 4;
    float* zbuf = (float*)w; w += (size_t)64 * 128 * 4;
    float* pen = (float*)w;

    hipMemsetAsync(zbuf, 0, (64 * 128 + 1) * sizeof(float), stream); // zbuf + pen

    convert_stats<<<dim3(64, 16), 256, 0, stream>>>(x, xb, p1, p2);
    prep_all<<<3592, 256, 0, stream>>>(
        W[0], W[1], W[2], W[3], w1t, w2t, w3t, w4t,
        bb[0], gg[0], be[0], mm[0], vv[0],
        bb[1], gg[1], be[1], mm[1], vv[1],
        bb[2], gg[2], be[2], mm[2], vv[2],
        bb[3], gg[3], be[3], mm[3], vv[3], sb);

    gemm_bt<256><<<dim3(512, 2), 512, 0, stream>>>(xb, w1t, sb + 0,    sb + 512,  hA);
    gemm_bt<512><<<dim3(512, 2), 512, 0, stream>>>(hA, w2t, sb + 1024, sb + 1536, hB);
    gemm_bt<512><<<dim3(512, 2), 512, 0, stream>>>(hB, w3t, sb + 2048, sb + 2560, hA);
    gemm_bt<512><<<dim3(512, 2), 512, 0, stream>>>(hA, w4t, sb + 3072, sb + 3584, hB);

    compute_A<<<2048, 256, 0, stream>>>(hB, Wa, Ab);
    seg_softmax<<<64, 1024, 0, stream>>>(Ab, As, pen);
    pooled_k<<<dim3(64, 4, 8), 256, 0, stream>>>(As, hB, pp);
    head1<<<dim3(64, 9), 128, 0, stream>>>(pp, p1, p2, Wo1, zbuf);
    head2<<<64, 128, 0, stream>>>(zbuf, bo1, go, beo, mo, vo, Wo2, bo2,
                                  pen, (float*)d_out);
}

// Round 2
// 508.650 us; speedup vs baseline: 1.0188x; 1.0188x over previous
//
#include <hip/hip_runtime.h>
#include <cstdint>
#include <cstddef>

typedef __bf16 bf16;
typedef __bf16 bf16x4 __attribute__((ext_vector_type(4)));
typedef __bf16 bf16x8 __attribute__((ext_vector_type(8)));
typedef float  f32x4  __attribute__((ext_vector_type(4)));
typedef unsigned int uint;

#define EPS 1e-5f

// ---------------------------------------------------------------------------
// async global->LDS, 16B per lane. LDS dest is wave-uniform base + lane*16.
// ---------------------------------------------------------------------------
__device__ __forceinline__ void load_lds16(const void* g, void* l) {
    typedef __attribute__((address_space(1))) void gvoid;
    typedef __attribute__((address_space(3))) void lvoid;
    gvoid* gp = (gvoid*)(unsigned long long)(uintptr_t)g;
    lvoid* lp = (lvoid*)(unsigned int)(uintptr_t)l;
    __builtin_amdgcn_global_load_lds(gp, lp, 16, 0, 0);
}

// ---------------------------------------------------------------------------
// fused: x -> bf16 copy + per-(b,d) partial sums for mean/std. grid (64,16)
// ---------------------------------------------------------------------------
__global__ __launch_bounds__(256)
void convert_stats(const float* __restrict__ x, bf16* __restrict__ xb,
                   float* __restrict__ p1, float* __restrict__ p2)
{
    const int b = blockIdx.x, lc = blockIdx.y, d = threadIdx.x;
    const size_t base = ((size_t)b * 1024 + lc * 64) * 256;
    float s = 0.f, s2 = 0.f;
    #pragma unroll 4
    for (int l = 0; l < 64; l++) {
        float v = x[base + (size_t)l * 256 + d];
        xb[base + (size_t)l * 256 + d] = (bf16)v;
        s += v; s2 += v * v;
    }
    p1[((size_t)lc * 64 + b) * 256 + d] = s;
    p2[((size_t)lc * 64 + b) * 256 + d] = s2;
}

// ---------------------------------------------------------------------------
// all weight prep in ONE dispatch: 4 transposes + 4 scale/bias. 3592 blocks.
// ---------------------------------------------------------------------------
__global__ void prep_all(
    const float* __restrict__ W1, const float* __restrict__ W2,
    const float* __restrict__ W3, const float* __restrict__ W4,
    bf16* __restrict__ t1, bf16* __restrict__ t2,
    bf16* __restrict__ t3, bf16* __restrict__ t4,
    const float* b1, const float* g1, const float* be1, const float* m1, const float* v1,
    const float* b2, const float* g2, const float* be2, const float* m2, const float* v2,
    const float* b3, const float* g3, const float* be3, const float* m3, const float* v3,
    const float* b4, const float* g4, const float* be4, const float* m4, const float* v4,
    float* __restrict__ sb)
{
    const int bid = blockIdx.x, tid = threadIdx.x;
    if (bid < 512) {                       // W1: 512x256 (Wt[n][k])
        int idx = bid * 256 + tid;
        int n = idx >> 8, k = idx & 255;
        t1[idx] = (bf16)W1[k * 512 + n];
    } else if (bid < 3584) {               // W2/W3/W4: 512x512 each
        int r = bid - 512;
        int which = r >> 10;               // 1024 blocks each
        int idx = (r & 1023) * 256 + tid;
        int n = idx >> 9, k = idx & 511;
        const float* W = which == 0 ? W2 : (which == 1 ? W3 : W4);
        bf16* Wt       = which == 0 ? t2 : (which == 1 ? t3 : t4);
        Wt[idx] = (bf16)W[k * 512 + n];
    } else {                               // scale/bias: 8 blocks
        int r = bid - 3584;
        int lay = r >> 1;
        int j = (r & 1) * 256 + tid;
        const float *b, *g, *be, *m, *v;
        switch (lay) {
            case 0: b=b1; g=g1; be=be1; m=m1; v=v1; break;
            case 1: b=b2; g=g2; be=be2; m=m2; v=v2; break;
            case 2: b=b3; g=g3; be=be3; m=m3; v=v3; break;
            default:b=b4; g=g4; be=be4; m=m4; v=v4; break;
        }
        float sj = g[j] * rsqrtf(v[j] + EPS);
        sb[lay * 1024 + j]       = sj;
        sb[lay * 1024 + 512 + j] = (b[j] - m[j]) * sj + be[j];
    }
}

// ---------------------------------------------------------------------------
// GEMM: C[M,512] = relu( (A[M,K] @ Wt[512,K]^T) * s + t ), bf16 out
// 128x256 tile, BK=32, 512 threads = 8 waves (2m x 4n), wave tile 64x64.
//
// T3+T4 pipeline: DOUBLE-BUFFERED LDS + COUNTED vmcnt (never 0 in the loop).
// Per wave, 3 global_load_lds per K-tile. Steady state per iter t:
//   vmcnt(3)                -- drain tile t's 3 loads; tile t+1's stay in flight
//   s_barrier               -- all waves' tile-t data visible in buf[t&1]
//   ds_read frags -> regs
//   lgkmcnt(0); s_barrier   -- every wave's reads landed => buf[t&1] is free
//   STAGE(t+2 -> buf[t&1])  -- loads fly under this iter's MFMA + next iter
//   16 x MFMA
// Last iter uses vmcnt(0). All barriers are inline-asm with "memory" clobber
// so the compiler cannot insert a full vmcnt(0)+lgkmcnt(0) drain (the m97
// structural stall).
//
// LDS layout is SUBTILED per 16-row fragment block: [blk][lane][8 bf16] so
// ds_read_b128 is conflict-free (verified: bank conflicts = 0) and the
// global_load_lds linear dest is matched by a permuted per-lane source.
// ---------------------------------------------------------------------------
template<int K>
__global__ __launch_bounds__(512, 4)
void gemm_bt(const bf16* __restrict__ A, const bf16* __restrict__ Bt,
             const float* __restrict__ sc, const float* __restrict__ bi,
             bf16* __restrict__ C)
{
    __shared__ __align__(16) bf16 As[2][128 * 32];   // 2 x 8 KB
    __shared__ __align__(16) bf16 Bs[2][256 * 32];   // 2 x 16 KB
    constexpr int NT = K / 32;

    const int tid  = threadIdx.x;
    const int lane = tid & 63;
    const int wid  = tid >> 6;            // 0..7
    const int wm   = wid >> 2;            // 0..1 (m half)
    const int wn   = wid & 3;             // 0..3 (n quarter)
    const size_t m0 = (size_t)blockIdx.x * 128;
    const int    n0 = blockIdx.y * 256;

    const int quad = lane >> 4;
    const int l16  = lane & 15;

    // staging: source row/col for this lane's 16B (subtiled permutation)
    const int srow = wid * 16 + l16;      // 0..127
    const int scol = quad * 8;            // 0,8,16,24

    bf16* AsW[2] = { &As[0][wid * 512], &As[1][wid * 512] };
    bf16* BsW[2] = { &Bs[0][wid * 512], &Bs[1][wid * 512] };

    const bf16* Arow  = &A [(m0 + srow) * K];
    const bf16* Brow0 = &Bt[(size_t)(n0 +       srow) * K];
    const bf16* Brow1 = &Bt[(size_t)(n0 + 128 + srow) * K];

    #define STAGE(t, b) do {                                   \
        const int k0_ = (t) * 32 + scol;                       \
        load_lds16(&Arow [k0_], AsW[b]);                       \
        load_lds16(&Brow0[k0_], BsW[b]);                       \
        load_lds16(&Brow1[k0_], BsW[b] + 4096);                \
    } while (0)

    f32x4 acc[4][4] = {};

    STAGE(0, 0);
    if (NT > 1) STAGE(1, 1);

    for (int t = 0; t < NT; ++t) {
        if (t < NT - 1) { asm volatile("s_waitcnt vmcnt(3)" ::: "memory"); }
        else            { asm volatile("s_waitcnt vmcnt(0)" ::: "memory"); }
        asm volatile("s_barrier" ::: "memory");

        const bf16* Ab_ = &As[t & 1][0];
        const bf16* Bb_ = &Bs[t & 1][0];
        bf16x8 af[4], bfr[4];
        #pragma unroll
        for (int i = 0; i < 4; i++)
            af[i] = *(const bf16x8*)&Ab_[((wm * 4 + i) * 64 + lane) * 8];
        #pragma unroll
        for (int j = 0; j < 4; j++)
            bfr[j] = *(const bf16x8*)&Bb_[((wn * 4 + j) * 64 + lane) * 8];

        asm volatile("s_waitcnt lgkmcnt(0)" ::: "memory");  // my reads landed
        asm volatile("s_barrier" ::: "memory");             // everyone's did

        if (t + 2 < NT) STAGE(t + 2, t & 1);                // overwrite freed buf

        #pragma unroll
        for (int i = 0; i < 4; i++)
            #pragma unroll
            for (int j = 0; j < 4; j++)
                acc[i][j] = __builtin_amdgcn_mfma_f32_16x16x32_bf16(af[i], bfr[j], acc[i][j], 0, 0, 0);
    }
    #undef STAGE

    // epilogue: C/D layout col = lane&15, row = quad*4 + r  [m89/m91 verified]
    #pragma unroll
    for (int j = 0; j < 4; j++) {
        const int col = n0 + wn * 64 + j * 16 + l16;
        const float s = sc[col], t = bi[col];
        #pragma unroll
        for (int i = 0; i < 4; i++) {
            const size_t rowb = m0 + wm * 64 + i * 16 + quad * 4;
            #pragma unroll
            for (int r = 0; r < 4; r++) {
                float v = acc[i][j][r] * s + t;
                v = v > 0.f ? v : 0.f;
                C[(rowb + r) * 512 + col] = (bf16)v;
            }
        }
    }
}

// ---------------------------------------------------------------------------
// A[N,8] = h4[N,512](bf16) @ Wa[512,8](f32)
// ---------------------------------------------------------------------------
__global__ __launch_bounds__(256)
void compute_A(const bf16* __restrict__ h, const float* __restrict__ Wa,
               float* __restrict__ A)
{
    __shared__ float WaL[512 * 8];
    const int tid = threadIdx.x;
    for (int i = tid; i < 4096; i += 256) WaL[i] = Wa[i];
    __syncthreads();
    const size_t row = (size_t)blockIdx.x * 32 + (tid >> 3);
    const int r = tid & 7;
    const bf16* hp = h + row * 512;
    float acc0 = 0.f, acc1 = 0.f;
    #pragma unroll 4
    for (int k8 = 0; k8 < 64; k8 += 2) {
        bf16x8 h0 = *(const bf16x8*)&hp[k8 * 8];
        bf16x8 h1 = *(const bf16x8*)&hp[k8 * 8 + 8];
        #pragma unroll
        for (int j = 0; j < 8; j++) {
            acc0 += (float)h0[j] * WaL[(k8 * 8 + j) * 8 + r];
            acc1 += (float)h1[j] * WaL[(k8 * 8 + 8 + j) * 8 + r];
        }
    }
    A[row * 8 + r] = acc0 + acc1;
}

// ---------------------------------------------------------------------------
// per-segment softmax over L (8 cols) + penalty. 1024 threads.
// ---------------------------------------------------------------------------
__global__ __launch_bounds__(1024)
void seg_softmax(const float* __restrict__ A, float* __restrict__ Asg,
                 float* __restrict__ pen)
{
    __shared__ float AsL[8192];
    __shared__ float red[1024];
    __shared__ float amax[8], asum[8];
    const int b = blockIdx.x, tid = threadIdx.x;
    const float* Ab = A + (size_t)b * 8192;
    for (int i = tid * 4; i < 8192; i += 4096)
        *(float4*)&AsL[i] = *(const float4*)&Ab[i];
    __syncthreads();
    const int r = tid & 7, chunk = tid >> 3;      // 128 chunks x 8 rows
    float pm = -1e30f;
    for (int l = chunk * 8; l < chunk * 8 + 8; l++) pm = fmaxf(pm, AsL[l * 8 + r]);
    red[tid] = pm;
    __syncthreads();
    if (tid < 512) red[tid] = fmaxf(red[tid], red[tid + 512]); __syncthreads();
    if (tid < 256) red[tid] = fmaxf(red[tid], red[tid + 256]); __syncthreads();
    if (tid < 128) red[tid] = fmaxf(red[tid], red[tid + 128]); __syncthreads();
    if (tid <  64) red[tid] = fmaxf(red[tid], red[tid +  64]); __syncthreads();
    if (tid <  32) red[tid] = fmaxf(red[tid], red[tid +  32]); __syncthreads();
    if (tid <  16) red[tid] = fmaxf(red[tid], red[tid +  16]); __syncthreads();
    if (tid <   8) amax[tid] = fmaxf(red[tid], red[tid + 8]);  __syncthreads();
    const float mr = amax[r];
    float ps = 0.f;
    for (int l = chunk * 8; l < chunk * 8 + 8; l++) {
        float e = expf(AsL[l * 8 + r] - mr);
        AsL[l * 8 + r] = e;
        ps += e;
    }
    red[tid] = ps;
    __syncthreads();
    if (tid < 512) red[tid] += red[tid + 512]; __syncthreads();
    if (tid < 256) red[tid] += red[tid + 256]; __syncthreads();
    if (tid < 128) red[tid] += red[tid + 128]; __syncthreads();
    if (tid <  64) red[tid] += red[tid +  64]; __syncthreads();
    if (tid <  32) red[tid] += red[tid +  32]; __syncthreads();
    if (tid <  16) red[tid] += red[tid +  16]; __syncthreads();
    if (tid <   8) asum[tid] = red[tid] + red[tid + 8];        __syncthreads();
    const float inv = 1.f / asum[r];
    for (int l = chunk * 8; l < chunk * 8 + 8; l++) AsL[l * 8 + r] *= inv;
    __syncthreads();
    for (int i = tid * 4; i < 8192; i += 4096)
        *(float4*)&Asg[(size_t)b * 8192 + i] = *(const float4*)&AsL[i];
    __syncthreads();
    // penalty: 64 (rr,ss) pairs x 16 l-chunks of 64
    {
        const int p = tid & 63, ch = tid >> 6;
        const int rr = p >> 3, ss = p & 7;
        float dot = 0.f;
        for (int l = ch * 64; l < ch * 64 + 64; l++)
            dot += AsL[l * 8 + rr] * AsL[l * 8 + ss];
        red[tid] = dot;
    }
    __syncthreads();
    if (tid < 512) red[tid] += red[tid + 512]; __syncthreads();
    if (tid < 256) red[tid] += red[tid + 256]; __syncthreads();
    if (tid < 128) red[tid] += red[tid + 128]; __syncthreads();
    if (tid < 64) {
        float d = red[tid] + red[tid + 64] - 1.f;
        red[tid] = d * d;
    }
    __syncthreads();
    if (tid == 0) {
        float s = 0.f;
        for (int i = 0; i < 64; i++) s += red[i];
        atomicAdd(pen, s);
    }
}

// ---------------------------------------------------------------------------
// pooled partials: grid (64, 4 col-chunks, 8 l-chunks of 128)
// ---------------------------------------------------------------------------
__global__ __launch_bounds__(256)
void pooled_k(const float* __restrict__ Asg, const bf16* __restrict__ h,
              float* __restrict__ pp)
{
    const int b = blockIdx.x;
    const int cc0 = blockIdx.y * 128;
    const int lc = blockIdx.z;
    const int tid = threadIdx.x;
    const int c = tid & 127, rg = tid >> 7;
    float a0 = 0, a1 = 0, a2 = 0, a3 = 0;
    const float* Asb = Asg + (size_t)b * 8192 + (size_t)lc * 128 * 8 + rg * 4;
    const bf16* hb = h + ((size_t)b * 1024 + lc * 128) * 512 + cc0 + c;
    #pragma unroll 4
    for (int l = 0; l < 128; l++) {
        float4 a = *(const float4*)&Asb[(size_t)l * 8];
        float hv = (float)hb[(size_t)l * 512];
        a0 += a.x * hv; a1 += a.y * hv; a2 += a.z * hv; a3 += a.w * hv;
    }
    float* pb = pp + ((size_t)lc * 64 + b) * 4096 + (rg * 4) * 512 + cc0 + c;
    pb[0] = a0; pb[512] = a1; pb[1024] = a2; pb[1536] = a3;
}

// ---------------------------------------------------------------------------
// head pass 1: z[b][c] += feat-chunk @ Wo1-slice. grid (64, 9)
// kc==8 computes mean/std inline from the convert_stats partials.
// ---------------------------------------------------------------------------
__global__ __launch_bounds__(128)
void head1(const float* __restrict__ pp, const float* __restrict__ p1,
           const float* __restrict__ p2, const float* __restrict__ Wo1,
           float* __restrict__ zbuf)
{
    __shared__ float f[512];
    const int b = blockIdx.x, kc = blockIdx.y, tid = threadIdx.x;
    if (kc < 8) {
        for (int j = tid; j < 512; j += 128) {
            const size_t i = (size_t)kc * 512 + j;
            float s = 0.f;
            #pragma unroll
            for (int lc = 0; lc < 8; lc++)
                s += pp[((size_t)lc * 64 + b) * 4096 + i];
            f[j] = s;
        }
    } else {
        for (int j = tid; j < 256; j += 128) {
            float s = 0.f, s2 = 0.f;
            #pragma unroll
            for (int lc = 0; lc < 16; lc++) {
                s  += p1[((size_t)lc * 64 + b) * 256 + j];
                s2 += p2[((size_t)lc * 64 + b) * 256 + j];
            }
            float m = s * (1.f / 1024.f);
            float var = (s2 - s * m) * (1.f / 1023.f);
            f[j]       = m;
            f[256 + j] = sqrtf(fmaxf(var, 0.f));
        }
    }
    __syncthreads();
    const float* Wp = Wo1 + (size_t)kc * 512 * 128 + tid;
    float z = 0.f;
    #pragma unroll 8
    for (int j = 0; j < 512; j++) z += f[j] * Wp[(size_t)j * 128];
    atomicAdd(&zbuf[b * 128 + tid], z);
}

// ---------------------------------------------------------------------------
// head pass 2: BN+relu -> @ Wo2 -> log_softmax; b==0 writes penalty
// ---------------------------------------------------------------------------
__global__ __launch_bounds__(128)
void head2(const float* __restrict__ zbuf, const float* __restrict__ bo1,
           const float* __restrict__ go, const float* __restrict__ beo,
           const float* __restrict__ mo, const float* __restrict__ vo,
           const float* __restrict__ Wo2, const float* __restrict__ bo2,
           const float* __restrict__ pen, float* __restrict__ out)
{
    __shared__ float o[128];
    __shared__ float lg[4];
    const int b = blockIdx.x, tid = threadIdx.x;
    float z = zbuf[b * 128 + tid];
    float s = go[tid] * rsqrtf(vo[tid] + EPS);
    float t = (bo1[tid] - mo[tid]) * s + beo[tid];
    float ov = z * s + t;
    o[tid] = ov > 0.f ? ov : 0.f;
    __syncthreads();
    if (tid < 4) {
        float acc = bo2[tid];
        for (int j = 0; j < 128; j++) acc += o[j] * Wo2[j * 4 + tid];
        lg[tid] = acc;
    }
    __syncthreads();
    if (tid == 0) {
        float m = fmaxf(fmaxf(lg[0], lg[1]), fmaxf(lg[2], lg[3]));
        float sum = 0.f;
        for (int k = 0; k < 4; k++) sum += expf(lg[k] - m);
        float lse = m + logf(sum);
        for (int k = 0; k < 4; k++) out[b * 4 + k] = lg[k] - lse;
        if (b == 0) out[256] = pen[0];
    }
}

// ---------------------------------------------------------------------------
extern "C" void kernel_launch(void* const* d_in, const int* in_sizes, int n_in,
                              void* d_out, int out_size, void* d_ws, size_t ws_size,
                              hipStream_t stream)
{
    const float* x   = (const float*)d_in[0];
    const float* Wa  = (const float*)d_in[2];
    const float* Wo1 = (const float*)d_in[3];
    const float* bo1 = (const float*)d_in[4];
    const float* go  = (const float*)d_in[5];
    const float* beo = (const float*)d_in[6];
    const float* mo  = (const float*)d_in[7];
    const float* vo  = (const float*)d_in[8];
    const float* Wo2 = (const float*)d_in[9];
    const float* bo2 = (const float*)d_in[10];
    const float *W[4], *bb[4], *gg[4], *be[4], *mm[4], *vv[4];
    for (int l = 0; l < 4; l++) {
        W[l]  = (const float*)d_in[11 + 6 * l + 0];
        bb[l] = (const float*)d_in[11 + 6 * l + 1];
        gg[l] = (const float*)d_in[11 + 6 * l + 2];
        be[l] = (const float*)d_in[11 + 6 * l + 3];
        mm[l] = (const float*)d_in[11 + 6 * l + 4];
        vv[l] = (const float*)d_in[11 + 6 * l + 5];
    }

    char* w = (char*)d_ws;
    bf16* xb  = (bf16*)w;  w += (size_t)65536 * 256 * 2;   // 32 MB
    bf16* hA  = (bf16*)w;  w += (size_t)65536 * 512 * 2;   // 64 MB
    bf16* hB  = (bf16*)w;  w += (size_t)65536 * 512 * 2;   // 64 MB
    bf16* w1t = (bf16*)w;  w += (size_t)512 * 256 * 2;
    bf16* w2t = (bf16*)w;  w += (size_t)512 * 512 * 2;
    bf16* w3t = (bf16*)w;  w += (size_t)512 * 512 * 2;
    bf16* w4t = (bf16*)w;  w += (size_t)512 * 512 * 2;
    float* sb = (float*)w; w += (size_t)4 * 1024 * 4;      // [layer][s|t][512]
    float* Ab = (float*)w; w += (size_t)65536 * 8 * 4;
    float* As = (float*)w; w += (size_t)65536 * 8 * 4;
    float* pp = (float*)w; w += (size_t)8 * 64 * 4096 * 4; // pooled partials
    float* p1 = (float*)w; w += (size_t)16 * 64 * 256 * 4;
    float* p2 = (float*)w; w += (size_t)16 * 64 * 256 * 4;
    float* zbuf = (float*)w; w += (size_t)64 * 128 * 4;
    float* pen = (float*)w;

    hipMemsetAsync(zbuf, 0, (64 * 128 + 1) * sizeof(float), stream); // zbuf + pen

    convert_stats<<<dim3(64, 16), 256, 0, stream>>>(x, xb, p1, p2);
    prep_all<<<3592, 256, 0, stream>>>(
        W[0], W[1], W[2], W[3], w1t, w2t, w3t, w4t,
        bb[0], gg[0], be[0], mm[0], vv[0],
        bb[1], gg[1], be[1], mm[1], vv[1],
        bb[2], gg[2], be[2], mm[2], vv[2],
        bb[3], gg[3], be[3], mm[3], vv[3], sb);

    gemm_bt<256><<<dim3(512, 2), 512, 0, stream>>>(xb, w1t, sb + 0,    sb + 512,  hA);
    gemm_bt<512><<<dim3(512, 2), 512, 0, stream>>>(hA, w2t, sb + 1024, sb + 1536, hB);
    gemm_bt<512><<<dim3(512, 2), 512, 0, stream>>>(hB, w3t, sb + 2048, sb + 2560, hA);
    gemm_bt<512><<<dim3(512, 2), 512, 0, stream>>>(hA, w4t, sb + 3072, sb + 3584, hB);

    compute_A<<<2048, 256, 0, stream>>>(hB, Wa, Ab);
    seg_softmax<<<64, 1024, 0, stream>>>(Ab, As, pen);
    pooled_k<<<dim3(64, 4, 8), 256, 0, stream>>>(As, hB, pp);
    head1<<<dim3(64, 9), 128, 0, stream>>>(pp, p1, p2, Wo1, zbuf);
    head2<<<64, 128, 0, stream>>>(zbuf, bo1, go, beo, mo, vo, Wo2, bo2,
                                  pen, (float*)d_out);
}